// Round 1
// baseline (126.102 us; speedup 1.0000x reference)
//
#include <hip/hip_runtime.h>
#include <hip/hip_bf16.h>
#include <math.h>

// MoE gate: logits = x[16384,8192] @ W[8,8192]^T ; top-2 softmax scattered
// into dense [16384,8] fp32 output. Memory-bound on streaming x (512 MiB).

#define D 8192
#define NE 8
#define CHUNK 1024              // features per LDS-staged W chunk
#define NCH (D / CHUNK)         // 8
#define TPW 4                   // tokens per wave
#define WAVES 4                 // waves per block
#define TPB (TPW * WAVES)       // 16 tokens per block

__global__ __launch_bounds__(256) void gate_kernel(const float* __restrict__ x,
                                                   const float* __restrict__ W,
                                                   float* __restrict__ out) {
    __shared__ float Wl[NE][CHUNK];   // 32 KiB

    const int tid  = threadIdx.x;
    const int wave = tid >> 6;
    const int lane = tid & 63;
    const int tokBase = blockIdx.x * TPB + wave * TPW;

    float acc[TPW][NE];
#pragma unroll
    for (int t = 0; t < TPW; ++t)
#pragma unroll
        for (int e = 0; e < NE; ++e) acc[t][e] = 0.0f;

    for (int ch = 0; ch < NCH; ++ch) {
        __syncthreads();   // protect previous chunk's LDS reads
        // stage W chunk: each thread loads one float4 per expert row
#pragma unroll
        for (int e = 0; e < NE; ++e) {
            float4 wv = *(const float4*)&W[e * D + ch * CHUNK + tid * 4];
            *(float4*)&Wl[e][tid * 4] = wv;
        }
        __syncthreads();

#pragma unroll
        for (int p = 0; p < CHUNK / 256; ++p) {   // 4 passes of 256 features
            const int f = p * 256 + lane * 4;     // offset within chunk
            float4 xv[TPW];
#pragma unroll
            for (int t = 0; t < TPW; ++t)
                xv[t] = *(const float4*)&x[(size_t)(tokBase + t) * D + ch * CHUNK + f];
#pragma unroll
            for (int e = 0; e < NE; ++e) {
                float4 wv = *(const float4*)&Wl[e][f];
#pragma unroll
                for (int t = 0; t < TPW; ++t) {
                    acc[t][e] += xv[t].x * wv.x;
                    acc[t][e] += xv[t].y * wv.y;
                    acc[t][e] += xv[t].z * wv.z;
                    acc[t][e] += xv[t].w * wv.w;
                }
            }
        }
    }

    // wave-wide butterfly reduction (wave = 64 lanes)
#pragma unroll
    for (int t = 0; t < TPW; ++t)
#pragma unroll
        for (int e = 0; e < NE; ++e) {
            float v = acc[t][e];
#pragma unroll
            for (int off = 32; off; off >>= 1) v += __shfl_xor(v, off, 64);
            acc[t][e] = v;   // now wave-uniform full dot product
        }

    // top-2 + softmax + dense scatter (all lanes compute; lanes 0..7 store)
#pragma unroll
    for (int t = 0; t < TPW; ++t) {
        float b1 = acc[t][0]; int i1 = 0;
#pragma unroll
        for (int e = 1; e < NE; ++e)
            if (acc[t][e] > b1) { b1 = acc[t][e]; i1 = e; }
        float b2 = -INFINITY; int i2 = 0;
#pragma unroll
        for (int e = 0; e < NE; ++e)
            if (e != i1 && acc[t][e] > b2) { b2 = acc[t][e]; i2 = e; }
        // softmax over [b1, b2]: q = e^(b2-b1) <= 1
        float q  = expf(b2 - b1);
        float p1 = 1.0f / (1.0f + q);
        float p2 = q * p1;
        if (lane < NE) {
            float v = (lane == i1) ? p1 : ((lane == i2) ? p2 : 0.0f);
            out[(size_t)(tokBase + t) * NE + lane] = v;
        }
    }
}

extern "C" void kernel_launch(void* const* d_in, const int* in_sizes, int n_in,
                              void* d_out, int out_size, void* d_ws, size_t ws_size,
                              hipStream_t stream) {
    const float* x = (const float*)d_in[0];
    const float* W = (const float*)d_in[1];
    float* out = (float*)d_out;

    const int n_tokens = 16384;          // 2*4*2048
    const int grid = n_tokens / TPB;     // 1024 blocks
    gate_kernel<<<grid, 256, 0, stream>>>(x, W, out);
}